// Round 1
// baseline (870.541 us; speedup 1.0000x reference)
//
#include <hip/hip_runtime.h>
#include <math.h>

#define T_TOK 2048
#define DM 1024
#define HQ 16
#define HD 64
#define NB 32
#define BS 64
#define S_SEL 16
#define NEGF (-1e30f)

// ---------------- GEMM: Y[M,N] = X[M,K] @ W[N,K]^T (both K-major) -------------
__global__ __launch_bounds__(256) void gemm_nt(const float* __restrict__ X,
    const float* __restrict__ W, float* __restrict__ Y,
    int M, int N, int K)
{
  __shared__ float Xs[16][68];   // [k][m], stride 68: 16B-aligned rows, 2-way max
  __shared__ float Ws[16][68];   // [k][n]
  const int tid = threadIdx.x;
  const int m0 = blockIdx.y * 64, n0 = blockIdx.x * 64;
  const int tx = tid & 15, ty = tid >> 4;
  const int lr = tid >> 2, lc = (tid & 3) * 4;
  float acc[4][4] = {};
  for (int k0 = 0; k0 < K; k0 += 16) {
    float4 xv = *(const float4*)(X + (size_t)(m0 + lr) * K + k0 + lc);
    float4 wv = make_float4(0.f, 0.f, 0.f, 0.f);
    if (n0 + lr < N) wv = *(const float4*)(W + (size_t)(n0 + lr) * K + k0 + lc);
    Xs[lc+0][lr] = xv.x; Xs[lc+1][lr] = xv.y; Xs[lc+2][lr] = xv.z; Xs[lc+3][lr] = xv.w;
    Ws[lc+0][lr] = wv.x; Ws[lc+1][lr] = wv.y; Ws[lc+2][lr] = wv.z; Ws[lc+3][lr] = wv.w;
    __syncthreads();
    #pragma unroll
    for (int kk = 0; kk < 16; ++kk) {
      float4 a = *(const float4*)&Xs[kk][ty*4];
      float4 b = *(const float4*)&Ws[kk][tx*4];
      acc[0][0] += a.x*b.x; acc[0][1] += a.x*b.y; acc[0][2] += a.x*b.z; acc[0][3] += a.x*b.w;
      acc[1][0] += a.y*b.x; acc[1][1] += a.y*b.y; acc[1][2] += a.y*b.z; acc[1][3] += a.y*b.w;
      acc[2][0] += a.z*b.x; acc[2][1] += a.z*b.y; acc[2][2] += a.z*b.z; acc[2][3] += a.z*b.w;
      acc[3][0] += a.w*b.x; acc[3][1] += a.w*b.y; acc[3][2] += a.w*b.z; acc[3][3] += a.w*b.w;
    }
    __syncthreads();
  }
  #pragma unroll
  for (int i = 0; i < 4; ++i) {
    int m = m0 + ty*4 + i;
    #pragma unroll
    for (int j = 0; j < 4; ++j) {
      int n = n0 + tx*4 + j;
      if (n < N) Y[(size_t)m*N + n] = acc[i][j];
    }
  }
}

// ---------------- mean-pool k,v into 32 block centroids -----------------------
__global__ void pool_kv(const float* __restrict__ k, const float* __restrict__ v,
                        float* __restrict__ kc, float* __restrict__ vc)
{
  int c = blockIdx.x, d = threadIdx.x;
  float sk = 0.f, sv = 0.f;
  for (int i = 0; i < BS; ++i) {
    sk += k[(size_t)(c*BS + i)*HD + d];
    sv += v[(size_t)(c*BS + i)*HD + d];
  }
  kc[c*HD + d] = sk * (1.f/BS);
  vc[c*HD + d] = sv * (1.f/BS);
}

// ------ compressed attention + top-k block selection (one WG per token) -------
__global__ __launch_bounds__(256) void cmp_attn(const float* __restrict__ q,
    const float* __restrict__ kc, const float* __restrict__ vc,
    float* __restrict__ ocmp, int* __restrict__ blkp)
{
  const int t = blockIdx.x, tid = threadIdx.x;
  __shared__ float qs[1024];
  __shared__ float scs[16][33];
  __shared__ float ps[16][33];
  __shared__ float imps[32];
  ((float4*)qs)[tid] = ((const float4*)q)[(size_t)t*256 + tid];
  __syncthreads();
  // scores: 16 heads x 32 blocks = 512 dots of 64; 2 per thread
  #pragma unroll
  for (int p = 0; p < 2; ++p) {
    int pair = tid + 256*p;
    int h = pair >> 5, c = pair & 31;
    const float4* kc4 = (const float4*)(kc + c*HD);
    const float4* q4  = (const float4*)(qs + h*HD);
    float a = 0.f;
    #pragma unroll
    for (int d4 = 0; d4 < 16; ++d4) {
      float4 kv = kc4[d4], qv = q4[d4];
      a += qv.x*kv.x + qv.y*kv.y + qv.z*kv.z + qv.w*kv.w;
    }
    scs[h][c] = a * 0.125f;
  }
  __syncthreads();
  const int nvis = (t + 1) >> 6;            // fully-past blocks visible
  if (tid < 16) {
    int h = tid;
    float m = -INFINITY;
    for (int c = 0; c < nvis; ++c) m = fmaxf(m, scs[h][c]);
    float l = 0.f;
    for (int c = 0; c < nvis; ++c) { float e = expf(scs[h][c] - m); ps[h][c] = e; l += e; }
    float inv = (nvis > 0) ? 1.f/l : 0.f;
    for (int c = 0; c < 32; ++c) ps[h][c] = (c < nvis) ? ps[h][c]*inv : 0.f;
  }
  __syncthreads();
  // o_cmp = p @ v_c : 16x64 outputs, 4 per thread (head uniform per wave)
  #pragma unroll
  for (int jj = 0; jj < 4; ++jj) {
    int idx = tid + 256*jj;
    int h = idx >> 6, d = idx & 63;
    float a = 0.f;
    #pragma unroll 8
    for (int c = 0; c < 32; ++c) a += ps[h][c] * vc[c*HD + d];
    ocmp[(size_t)t*DM + idx] = a;
  }
  if (tid < 32) {
    float s = 0.f;
    for (int h = 0; h < 16; ++h) s += ps[h][tid];
    imps[tid] = s;
  }
  __syncthreads();
  // stable top-k (jax.lax.top_k: descending, ties -> smaller index first)
  if (tid == 0) {
    const int cur = t >> 6;
    float a[32];
    for (int c = 0; c < 32; ++c) a[c] = (c <= cur) ? imps[c] : NEGF;
    a[0] = INFINITY; a[cur] = INFINITY;
    unsigned taken = 0u;
    for (int s = 0; s < S_SEL; ++s) {
      float best = -INFINITY; int bi = 0;
      for (int c = 0; c < 32; ++c)
        if (!((taken >> c) & 1u) && a[c] > best) { best = a[c]; bi = c; }
      taken |= 1u << bi;
      blkp[t*S_SEL + s] = bi;
    }
  }
}

// ------ selected block-sparse attention; one WG per (token, 8-head group) -----
// Reads o_cmp and overwrites the same buffer with the gated combined output o.
#define SC_W 1040   // 1024 + pad: rows 16B-aligned, conflict-free phase-2 reads
__global__ __launch_bounds__(256) void sel_attn(const float* __restrict__ q,
    const float* __restrict__ k, const float* __restrict__ v,
    const float* __restrict__ gp, const int* __restrict__ blkp,
    float* ocmp_io)
{
  const int t = blockIdx.x, grp = blockIdx.y, tid = threadIdx.x;
  __shared__ float qs[512];          // this group's 8 heads
  __shared__ float sc[8][SC_W];      // scores, then exp(scores - m)
  __shared__ int   toks[1024];
  __shared__ int   blk_s[16];
  __shared__ float red[8][32];
  __shared__ float redm[8], redl[8];
  __shared__ float gcs[8], gss[8];

  if (tid < 128) ((float4*)qs)[tid] = ((const float4*)(q + (size_t)t*DM + grp*512))[tid];
  if (tid < 16) blk_s[tid] = blkp[t*S_SEL + tid];
  if (tid < 8) {
    int h = grp*8 + tid;
    float a = gp[(size_t)t*48 + h*3 + 0]; gcs[tid] = 1.f/(1.f + __expf(-a));
    float b = gp[(size_t)t*48 + h*3 + 1]; gss[tid] = 1.f/(1.f + __expf(-b));
  }
  __syncthreads();

  // phase 1: scores for 4 gathered tokens per thread x 8 heads
  float acc[4][8] = {};
  const int off = tid & 63, sb = tid >> 6;
  int tk[4];
  #pragma unroll
  for (int j = 0; j < 4; ++j) tk[j] = blk_s[sb + 4*j]*BS + off;
  const float4* k4  = (const float4*)k;
  const float4* qs4 = (const float4*)qs;
  #pragma unroll 4
  for (int d4 = 0; d4 < 16; ++d4) {
    float4 kv0 = k4[(size_t)tk[0]*16 + d4];
    float4 kv1 = k4[(size_t)tk[1]*16 + d4];
    float4 kv2 = k4[(size_t)tk[2]*16 + d4];
    float4 kv3 = k4[(size_t)tk[3]*16 + d4];
    #pragma unroll
    for (int h = 0; h < 8; ++h) {
      float4 qv = qs4[h*16 + d4];
      acc[0][h] += qv.x*kv0.x + qv.y*kv0.y + qv.z*kv0.z + qv.w*kv0.w;
      acc[1][h] += qv.x*kv1.x + qv.y*kv1.y + qv.z*kv1.z + qv.w*kv1.w;
      acc[2][h] += qv.x*kv2.x + qv.y*kv2.y + qv.z*kv2.z + qv.w*kv2.w;
      acc[3][h] += qv.x*kv3.x + qv.y*kv3.y + qv.z*kv3.z + qv.w*kv3.w;
    }
  }
  #pragma unroll
  for (int j = 0; j < 4; ++j) {
    int i = tid + 256*j;
    toks[i] = tk[j];
    bool ok = (tk[j] <= t);               // causal within gathered tokens
    #pragma unroll
    for (int h = 0; h < 8; ++h)
      sc[h][i] = ok ? acc[j][h]*0.125f : NEGF;
  }
  __syncthreads();

  // softmax per head (store un-normalized exp; fold 1/l into epilogue)
  {
    int h = tid >> 5, sub = tid & 31;
    float4* row = (float4*)&sc[h][0];
    float m = -INFINITY;
    #pragma unroll
    for (int r = 0; r < 8; ++r) {
      float4 xv = row[sub + 32*r];
      m = fmaxf(m, fmaxf(fmaxf(xv.x, xv.y), fmaxf(xv.z, xv.w)));
    }
    red[h][sub] = m;
    __syncthreads();
    if (tid < 8) {
      float mm = red[tid][0];
      for (int s2 = 1; s2 < 32; ++s2) mm = fmaxf(mm, red[tid][s2]);
      redm[tid] = mm;
    }
    __syncthreads();
    float mm = redm[h];
    float l = 0.f;
    #pragma unroll
    for (int r = 0; r < 8; ++r) {
      float4 xv = row[sub + 32*r];
      xv.x = __expf(xv.x - mm); xv.y = __expf(xv.y - mm);
      xv.z = __expf(xv.z - mm); xv.w = __expf(xv.w - mm);
      l += xv.x + xv.y + xv.z + xv.w;
      row[sub + 32*r] = xv;
    }
    red[h][sub] = l;
    __syncthreads();
    if (tid < 8) {
      float ll = 0.f;
      for (int s2 = 0; s2 < 32; ++s2) ll += red[tid][s2];
      redl[tid] = 1.f/ll;
    }
    __syncthreads();
  }

  // phase 2: o = p @ v_sel ; thread = (dim d, head-pair hb/hb+4)
  const int d = tid & 63, hb = tid >> 6;
  float oa0 = 0.f, oa1 = 0.f;
  #pragma unroll 4
  for (int i = 0; i < 1024; ++i) {
    float vv = v[(size_t)toks[i]*HD + d];
    oa0 += sc[hb][i]   * vv;
    oa1 += sc[hb+4][i] * vv;
  }
  #pragma unroll
  for (int j = 0; j < 2; ++j) {
    int hl = hb + 4*j;
    float oa = (j == 0) ? oa0 : oa1;
    int h = grp*8 + hl;
    size_t idx = (size_t)t*DM + h*HD + d;
    float val = oa * redl[hl] * gss[hl] + ocmp_io[idx] * gcs[hl];
    ocmp_io[idx] = val;                 // in-place: read-before-write, per-thread
  }
}

extern "C" void kernel_launch(void* const* d_in, const int* in_sizes, int n_in,
                              void* d_out, int out_size, void* d_ws, size_t ws_size,
                              hipStream_t stream)
{
  const float* x  = (const float*)d_in[0];
  const float* Wq = (const float*)d_in[1];
  const float* Wk = (const float*)d_in[2];
  const float* Wv = (const float*)d_in[3];
  const float* Wg = (const float*)d_in[4];
  const float* Wo = (const float*)d_in[5];
  float* out = (float*)d_out;

  float* ws  = (float*)d_ws;
  float* q    = ws;                          // T*DM
  float* kbuf = q    + (size_t)T_TOK*DM;     // T*HD
  float* vbuf = kbuf + (size_t)T_TOK*HD;     // T*HD
  float* gpj  = vbuf + (size_t)T_TOK*HD;     // T*48
  float* kc   = gpj  + (size_t)T_TOK*48;     // NB*HD
  float* vc   = kc   + NB*HD;                // NB*HD
  float* ocmp = vc   + NB*HD;                // T*DM (becomes combined o in-place)
  int*   blkp = (int*)(ocmp + (size_t)T_TOK*DM);  // T*S_SEL

  gemm_nt<<<dim3(DM/64, T_TOK/64), 256, 0, stream>>>(x, Wq, q,    T_TOK, DM, DM);
  gemm_nt<<<dim3(1,     T_TOK/64), 256, 0, stream>>>(x, Wk, kbuf, T_TOK, HD, DM);
  gemm_nt<<<dim3(1,     T_TOK/64), 256, 0, stream>>>(x, Wv, vbuf, T_TOK, HD, DM);
  gemm_nt<<<dim3(1,     T_TOK/64), 256, 0, stream>>>(x, Wg, gpj,  T_TOK, 48, DM);
  pool_kv<<<NB, HD, 0, stream>>>(kbuf, vbuf, kc, vc);
  cmp_attn<<<T_TOK, 256, 0, stream>>>(q, kc, vc, ocmp, blkp);
  sel_attn<<<dim3(T_TOK, 2), 256, 0, stream>>>(q, kbuf, vbuf, gpj, blkp, ocmp);
  gemm_nt<<<dim3(DM/64, T_TOK/64), 256, 0, stream>>>(ocmp, Wo, out, T_TOK, DM, DM);
}

// Round 2
// 511.993 us; speedup vs baseline: 1.7003x; 1.7003x over previous
//
#include <hip/hip_runtime.h>
#include <math.h>

#define T_TOK 2048
#define DM 1024
#define HQ 16
#define HD 64
#define NB 32
#define BS 64
#define S_SEL 16
#define NEGF (-1e30f)

typedef __attribute__((ext_vector_type(8))) short bf16x8;
typedef __attribute__((ext_vector_type(4))) float f32x4;

__device__ __forceinline__ unsigned short f2bf(float x) {
  unsigned u = __float_as_uint(x);
  return (unsigned short)((u + 0x7fffu + ((u >> 16) & 1u)) >> 16);
}
__device__ __forceinline__ float bf2f(unsigned short h) {
  return __uint_as_float(((unsigned)h) << 16);
}

// ---------------- GEMM: Y[M,N] = X[M,K] @ W[N,K]^T (both K-major) -------------
__global__ __launch_bounds__(256) void gemm_nt(const float* __restrict__ X,
    const float* __restrict__ W, float* __restrict__ Y,
    int M, int N, int K)
{
  __shared__ float Xs[16][68];
  __shared__ float Ws[16][68];
  const int tid = threadIdx.x;
  const int m0 = blockIdx.y * 64, n0 = blockIdx.x * 64;
  const int tx = tid & 15, ty = tid >> 4;
  const int lr = tid >> 2, lc = (tid & 3) * 4;
  float acc[4][4] = {};
  for (int k0 = 0; k0 < K; k0 += 16) {
    float4 xv = *(const float4*)(X + (size_t)(m0 + lr) * K + k0 + lc);
    float4 wv = make_float4(0.f, 0.f, 0.f, 0.f);
    if (n0 + lr < N) wv = *(const float4*)(W + (size_t)(n0 + lr) * K + k0 + lc);
    Xs[lc+0][lr] = xv.x; Xs[lc+1][lr] = xv.y; Xs[lc+2][lr] = xv.z; Xs[lc+3][lr] = xv.w;
    Ws[lc+0][lr] = wv.x; Ws[lc+1][lr] = wv.y; Ws[lc+2][lr] = wv.z; Ws[lc+3][lr] = wv.w;
    __syncthreads();
    #pragma unroll
    for (int kk = 0; kk < 16; ++kk) {
      float4 a = *(const float4*)&Xs[kk][ty*4];
      float4 b = *(const float4*)&Ws[kk][tx*4];
      acc[0][0] += a.x*b.x; acc[0][1] += a.x*b.y; acc[0][2] += a.x*b.z; acc[0][3] += a.x*b.w;
      acc[1][0] += a.y*b.x; acc[1][1] += a.y*b.y; acc[1][2] += a.y*b.z; acc[1][3] += a.y*b.w;
      acc[2][0] += a.z*b.x; acc[2][1] += a.z*b.y; acc[2][2] += a.z*b.z; acc[2][3] += a.z*b.w;
      acc[3][0] += a.w*b.x; acc[3][1] += a.w*b.y; acc[3][2] += a.w*b.z; acc[3][3] += a.w*b.w;
    }
    __syncthreads();
  }
  #pragma unroll
  for (int i = 0; i < 4; ++i) {
    int m = m0 + ty*4 + i;
    #pragma unroll
    for (int j = 0; j < 4; ++j) {
      int n = n0 + tx*4 + j;
      if (n < N) Y[(size_t)m*N + n] = acc[i][j];
    }
  }
}

// ---------------- cast f32 -> bf16 (q, k, v in one contiguous range) ----------
__global__ __launch_bounds__(256) void cast_bf16(const float* __restrict__ src,
    unsigned short* __restrict__ dst, int n4)
{
  int i = blockIdx.x * 256 + threadIdx.x;
  if (i < n4) {
    float4 v = ((const float4*)src)[i];
    ushort4 o;
    o.x = f2bf(v.x); o.y = f2bf(v.y); o.z = f2bf(v.z); o.w = f2bf(v.w);
    ((ushort4*)dst)[i] = o;
  }
}

// ---------------- mean-pool k,v into 32 block centroids -----------------------
__global__ void pool_kv(const float* __restrict__ k, const float* __restrict__ v,
                        float* __restrict__ kc, float* __restrict__ vc)
{
  int c = blockIdx.x, d = threadIdx.x;
  float sk = 0.f, sv = 0.f;
  for (int i = 0; i < BS; ++i) {
    sk += k[(size_t)(c*BS + i)*HD + d];
    sv += v[(size_t)(c*BS + i)*HD + d];
  }
  kc[c*HD + d] = sk * (1.f/BS);
  vc[c*HD + d] = sv * (1.f/BS);
}

// ------ compressed attention + top-k block selection (one WG per token) -------
// Stays f32 end-to-end: block selection must match reference exactly.
__global__ __launch_bounds__(256) void cmp_attn(const float* __restrict__ q,
    const float* __restrict__ kc, const float* __restrict__ vc,
    float* __restrict__ ocmp, int* __restrict__ blkp)
{
  const int t = blockIdx.x, tid = threadIdx.x;
  __shared__ float qs[1024];
  __shared__ float scs[16][33];
  __shared__ float ps[16][33];
  __shared__ float imps[32];
  ((float4*)qs)[tid] = ((const float4*)q)[(size_t)t*256 + tid];
  __syncthreads();
  #pragma unroll
  for (int p = 0; p < 2; ++p) {
    int pair = tid + 256*p;
    int h = pair >> 5, c = pair & 31;
    const float4* kc4 = (const float4*)(kc + c*HD);
    const float4* q4  = (const float4*)(qs + h*HD);
    float a = 0.f;
    #pragma unroll
    for (int d4 = 0; d4 < 16; ++d4) {
      float4 kv = kc4[d4], qv = q4[d4];
      a += qv.x*kv.x + qv.y*kv.y + qv.z*kv.z + qv.w*kv.w;
    }
    scs[h][c] = a * 0.125f;
  }
  __syncthreads();
  const int nvis = (t + 1) >> 6;
  if (tid < 16) {
    int h = tid;
    float m = -INFINITY;
    for (int c = 0; c < nvis; ++c) m = fmaxf(m, scs[h][c]);
    float l = 0.f;
    for (int c = 0; c < nvis; ++c) { float e = expf(scs[h][c] - m); ps[h][c] = e; l += e; }
    float inv = (nvis > 0) ? 1.f/l : 0.f;
    for (int c = 0; c < 32; ++c) ps[h][c] = (c < nvis) ? ps[h][c]*inv : 0.f;
  }
  __syncthreads();
  #pragma unroll
  for (int jj = 0; jj < 4; ++jj) {
    int idx = tid + 256*jj;
    int h = idx >> 6, d = idx & 63;
    float a = 0.f;
    #pragma unroll 8
    for (int c = 0; c < 32; ++c) a += ps[h][c] * vc[c*HD + d];
    ocmp[(size_t)t*DM + idx] = a;
  }
  if (tid < 32) {
    float s = 0.f;
    for (int h = 0; h < 16; ++h) s += ps[h][tid];
    imps[tid] = s;
  }
  __syncthreads();
  if (tid == 0) {
    const int cur = t >> 6;
    float a[32];
    for (int c = 0; c < 32; ++c) a[c] = (c <= cur) ? imps[c] : NEGF;
    a[0] = INFINITY; a[cur] = INFINITY;
    unsigned taken = 0u;
    for (int s = 0; s < S_SEL; ++s) {
      float best = -INFINITY; int bi = 0;
      for (int c = 0; c < 32; ++c)
        if (!((taken >> c) & 1u) && a[c] > best) { best = a[c]; bi = c; }
      taken |= 1u << bi;
      blkp[t*S_SEL + s] = bi;
    }
  }
}

// ------ selected block-sparse attention via MFMA; one WG (4 waves) per token --
// S = Q K_sel^T (16x1024), register softmax, P->bf16 LDS, O = P V_sel (16x64).
// mfma_f32_16x16x32_bf16: A[m=lane&15][k=quad*8+j], B[k=quad*8+j][n=lane&15],
// C/D col=lane&15, row=quad*4+reg (guide §3, m89/m120-verified).
#define KSW 72      // Ks row stride (bf16): 64+8 -> 2-way banks max
#define VTW 136     // Vt row stride (bf16): 128+8
#define PBW 1032    // Pb row stride (bf16): 1024+8
__global__ __launch_bounds__(256) void sel_attn_mfma(
    const unsigned short* __restrict__ qb, const unsigned short* __restrict__ kb,
    const unsigned short* __restrict__ vb, const float* __restrict__ gp,
    const int* __restrict__ blkp, float* __restrict__ ocmp_io)
{
  const int t = blockIdx.x, tid = threadIdx.x;
  const int w = tid >> 6, lane = tid & 63;
  const int quad = lane >> 4, c = lane & 15;

  __shared__ unsigned short Pb[16][PBW];        // 33.0 KB  exp(S-m) bf16
  __shared__ unsigned short KV[64 * VTW];       // 17.4 KB  union: Ks / Vt
  __shared__ int   blk_s[16];
  __shared__ float redm[4][16], redl[4][16];
  __shared__ float gm[16], invl[16], gc[16], gs[16];

  if (tid < 16) {
    blk_s[tid] = blkp[t*S_SEL + tid];
    float a = gp[(size_t)t*48 + tid*3 + 0];
    float b = gp[(size_t)t*48 + tid*3 + 1];
    gc[tid] = 1.f/(1.f + __expf(-a));
    gs[tid] = 1.f/(1.f + __expf(-b));
  }

  // Q A-fragments (head m = c), held across the whole QK phase
  const unsigned short* qrow = qb + (size_t)t*DM + c*HD + quad*8;
  bf16x8 qa0 = *(const bf16x8*)(qrow);          // d in [quad*8, quad*8+8)
  bf16x8 qa1 = *(const bf16x8*)(qrow + 32);     // d in [32+quad*8, ...)

  // ---------------- phase 1: S = Q K^T, one 64-token block at a time ----------
  f32x4 S[16];
  for (int b = 0; b < 16; ++b) {
    __syncthreads();                            // KV reusable
    // stage K block (contiguous 8 KB of kb) into Ks rows (stride KSW)
    {
      const int base = blk_s[b] * (BS*HD);
      #pragma unroll
      for (int rep = 0; rep < 2; ++rep) {
        int i = tid*2 + rep;                    // 512 x 8-bf16 pieces
        int tok = i >> 3, colb = (i & 7) * 8;
        bf16x8 kvv = *(const bf16x8*)(kb + base + i*8);
        *(bf16x8*)&KV[tok*KSW + colb] = kvv;
      }
    }
    __syncthreads();
    const int srow = w*16 + c;                  // token within block (n = c)
    bf16x8 b0 = *(const bf16x8*)&KV[srow*KSW + quad*8];
    bf16x8 b1 = *(const bf16x8*)&KV[srow*KSW + 32 + quad*8];
    f32x4 acc = {0.f, 0.f, 0.f, 0.f};
    acc = __builtin_amdgcn_mfma_f32_16x16x32_bf16(qa0, b0, acc, 0, 0, 0);
    acc = __builtin_amdgcn_mfma_f32_16x16x32_bf16(qa1, b1, acc, 0, 0, 0);
    const int tok = blk_s[b]*BS + w*16 + c;
    const bool ok = (tok <= t);
    #pragma unroll
    for (int r = 0; r < 4; ++r) S[b][r] = ok ? acc[r]*0.125f : NEGF;
  }

  // ---------------- softmax over s (register + shuffle + LDS) ----------------
  f32x4 mx = S[0];
  #pragma unroll
  for (int b = 1; b < 16; ++b) {
    #pragma unroll
    for (int r = 0; r < 4; ++r) mx[r] = fmaxf(mx[r], S[b][r]);
  }
  #pragma unroll
  for (int off = 1; off < 16; off <<= 1) {
    #pragma unroll
    for (int r = 0; r < 4; ++r) mx[r] = fmaxf(mx[r], __shfl_xor(mx[r], off));
  }
  if (c == 0) {
    #pragma unroll
    for (int r = 0; r < 4; ++r) redm[w][quad*4 + r] = mx[r];
  }
  __syncthreads();
  if (tid < 16)
    gm[tid] = fmaxf(fmaxf(redm[0][tid], redm[1][tid]),
                    fmaxf(redm[2][tid], redm[3][tid]));
  __syncthreads();
  f32x4 M;
  #pragma unroll
  for (int r = 0; r < 4; ++r) M[r] = gm[quad*4 + r];

  f32x4 lsum = {0.f, 0.f, 0.f, 0.f};
  #pragma unroll
  for (int b = 0; b < 16; ++b) {
    #pragma unroll
    for (int r = 0; r < 4; ++r) {
      unsigned short pbv = f2bf(__expf(S[b][r] - M[r]));
      Pb[quad*4 + r][b*64 + w*16 + c] = pbv;
      lsum[r] += bf2f(pbv);
    }
  }
  #pragma unroll
  for (int off = 1; off < 16; off <<= 1) {
    #pragma unroll
    for (int r = 0; r < 4; ++r) lsum[r] += __shfl_xor(lsum[r], off);
  }
  if (c == 0) {
    #pragma unroll
    for (int r = 0; r < 4; ++r) redl[w][quad*4 + r] = lsum[r];
  }
  __syncthreads();
  if (tid < 16)
    invl[tid] = 1.f / (redl[0][tid] + redl[1][tid] + redl[2][tid] + redl[3][tid]);
  // (Pb fully written before this barrier)
  __syncthreads();

  // ---------------- phase 2: O = P V, 128 gathered tokens per chunk ----------
  f32x4 accO = {0.f, 0.f, 0.f, 0.f};
  const int p = tid & 63, dg = tid >> 6, d0 = dg*16;
  for (int ci = 0; ci < 8; ++ci) {
    __syncthreads();                            // prev Vt consumed / Ks done
    {
      const int tloc = 2*p;                     // token pair in chunk
      const int blk  = blk_s[2*ci + (tloc >> 6)];
      const int gtok = blk*BS + (tloc & 63);
      const unsigned short* v0 = vb + (size_t)gtok*HD + d0;
      bf16x8 a0 = *(const bf16x8*)(v0);
      bf16x8 a1 = *(const bf16x8*)(v0 + 8);
      bf16x8 c0 = *(const bf16x8*)(v0 + 64);
      bf16x8 c1 = *(const bf16x8*)(v0 + 72);
      #pragma unroll
      for (int i = 0; i < 8; ++i) {
        *(unsigned int*)&KV[(d0+i)*VTW + tloc]   = (unsigned short)a0[i] | ((unsigned int)(unsigned short)c0[i] << 16);
        *(unsigned int*)&KV[(d0+8+i)*VTW + tloc] = (unsigned short)a1[i] | ((unsigned int)(unsigned short)c1[i] << 16);
      }
    }
    __syncthreads();                            // Vt ready
    #pragma unroll
    for (int kk = 0; kk < 4; ++kk) {
      bf16x8 A = *(const bf16x8*)&Pb[c][128*ci + 32*kk + quad*8];
      bf16x8 B = *(const bf16x8*)&KV[(16*w + c)*VTW + 32*kk + quad*8];
      accO = __builtin_amdgcn_mfma_f32_16x16x32_bf16(A, B, accO, 0, 0, 0);
    }
  }

  // ---------------- epilogue: gate + combine with o_cmp ----------------------
  const int d = 16*w + c;
  #pragma unroll
  for (int r = 0; r < 4; ++r) {
    const int h = quad*4 + r;
    size_t idx = (size_t)t*DM + h*HD + d;
    float val = accO[r] * invl[h] * gs[h] + ocmp_io[idx] * gc[h];
    ocmp_io[idx] = val;
  }
}

extern "C" void kernel_launch(void* const* d_in, const int* in_sizes, int n_in,
                              void* d_out, int out_size, void* d_ws, size_t ws_size,
                              hipStream_t stream)
{
  const float* x  = (const float*)d_in[0];
  const float* Wq = (const float*)d_in[1];
  const float* Wk = (const float*)d_in[2];
  const float* Wv = (const float*)d_in[3];
  const float* Wg = (const float*)d_in[4];
  const float* Wo = (const float*)d_in[5];
  float* out = (float*)d_out;

  float* ws  = (float*)d_ws;
  float* q    = ws;                           // T*DM
  float* kbuf = q    + (size_t)T_TOK*DM;      // T*HD   (contiguous after q)
  float* vbuf = kbuf + (size_t)T_TOK*HD;      // T*HD   (contiguous after kbuf)
  float* gpj  = vbuf + (size_t)T_TOK*HD;      // T*48
  float* kc   = gpj  + (size_t)T_TOK*48;      // NB*HD
  float* vc   = kc   + NB*HD;                 // NB*HD
  float* ocmp = vc   + NB*HD;                 // T*DM
  int*   blkp = (int*)(ocmp + (size_t)T_TOK*DM);          // T*S_SEL
  unsigned short* qkvb = (unsigned short*)(blkp + T_TOK*S_SEL); // T*1152 bf16
  unsigned short* qb = qkvb;
  unsigned short* kb = qb + (size_t)T_TOK*DM;
  unsigned short* vb = kb + (size_t)T_TOK*HD;

  gemm_nt<<<dim3(DM/64, T_TOK/64), 256, 0, stream>>>(x, Wq, q,    T_TOK, DM, DM);
  gemm_nt<<<dim3(1,     T_TOK/64), 256, 0, stream>>>(x, Wk, kbuf, T_TOK, HD, DM);
  gemm_nt<<<dim3(1,     T_TOK/64), 256, 0, stream>>>(x, Wv, vbuf, T_TOK, HD, DM);
  gemm_nt<<<dim3(1,     T_TOK/64), 256, 0, stream>>>(x, Wg, gpj,  T_TOK, 48, DM);
  pool_kv<<<NB, HD, 0, stream>>>(kbuf, vbuf, kc, vc);
  // cast q,kbuf,vbuf (contiguous T*1152 floats) -> bf16 for the sel branch only
  {
    int n4 = T_TOK * (DM + 2*HD) / 4;
    cast_bf16<<<(n4 + 255)/256, 256, 0, stream>>>(q, qkvb, n4);
  }
  cmp_attn<<<T_TOK, 256, 0, stream>>>(q, kc, vc, ocmp, blkp);
  sel_attn_mfma<<<T_TOK, 256, 0, stream>>>(qb, kb, vb, gpj, blkp, ocmp);
  gemm_nt<<<dim3(DM/64, T_TOK/64), 256, 0, stream>>>(ocmp, Wo, out, T_TOK, DM, DM);
}

// Round 3
// 405.282 us; speedup vs baseline: 2.1480x; 1.2633x over previous
//
#include <hip/hip_runtime.h>
#include <math.h>

#define T_TOK 2048
#define DM 1024
#define HQ 16
#define HD 64
#define NB 32
#define BS 64
#define S_SEL 16
#define NEGF (-1e30f)

typedef __attribute__((ext_vector_type(8))) short bf16x8;
typedef __attribute__((ext_vector_type(4))) float f32x4;
typedef unsigned short ush;

__device__ __forceinline__ ush f2bf(float x) {
  unsigned u = __float_as_uint(x);
  return (ush)((u + 0x7fffu + ((u >> 16) & 1u)) >> 16);
}
__device__ __forceinline__ float bf2f(ush h) {
  return __uint_as_float(((unsigned)h) << 16);
}

// ---- decompose the 5 weight arrays into bf16 hi/lo planes (one launch) ------
__global__ __launch_bounds__(256) void split_w(
    const float* __restrict__ s0, const float* __restrict__ s1,
    const float* __restrict__ s2, const float* __restrict__ s3,
    const float* __restrict__ s4,
    ush* h0, ush* l0, ush* h1, ush* l1, ush* h2, ush* l2,
    ush* h3, ush* l3, ush* h4, ush* l4)
{
  const float* srcs[5] = {s0, s1, s2, s3, s4};
  ush* hs[5] = {h0, h1, h2, h3, h4};
  ush* ls[5] = {l0, l1, l2, l3, l4};
  const int ns[5] = {1048576, 65536, 65536, 49152, 1048576};
  int seg = blockIdx.y;
  int i = (blockIdx.x * 256 + threadIdx.x) * 4;
  if (i >= ns[seg]) return;
  float4 v = *(const float4*)(srcs[seg] + i);
  ushort4 hv, lv;
  hv.x = f2bf(v.x); lv.x = f2bf(v.x - bf2f(hv.x));
  hv.y = f2bf(v.y); lv.y = f2bf(v.y - bf2f(hv.y));
  hv.z = f2bf(v.z); lv.z = f2bf(v.z - bf2f(hv.z));
  hv.w = f2bf(v.w); lv.w = f2bf(v.w - bf2f(hv.w));
  *(ushort4*)(hs[seg] + i) = hv;
  *(ushort4*)(ls[seg] + i) = lv;
}

// ---- split-bf16 MFMA GEMM: Y[M,N] = X[M,K] @ W[N,K]^T, ~f32 accuracy --------
// X: f32 (hi/lo computed during staging). W: pre-split bf16 planes.
// A·B ~= Ah·Bh + Ah·Bl + Al·Bh  (3 MFMAs, rel err ~1e-5).
// Tile: M=128, N=64, BK=32. 4 waves in 2x2: wave tile 64m x 32n.
#define AW 40   // LDS row stride (bf16): 32+8, 80 B (16B-aligned, 2-way max)
__global__ __launch_bounds__(256) void gemm_split(const float* __restrict__ X,
    const ush* __restrict__ Wh, const ush* __restrict__ Wl,
    float* __restrict__ Y, int N, int K)
{
  __shared__ ush Ash[128][AW], Asl[128][AW];   // 10 KB each
  __shared__ ush Bsh[64][AW],  Bsl[64][AW];    // 5 KB each
  const int tid = threadIdx.x;
  const int n0 = blockIdx.x * 64, m0 = blockIdx.y * 128;
  const int wave = tid >> 6, lane = tid & 63;
  const int quad = lane >> 4, cc = lane & 15;
  const int wm = wave >> 1, wn = wave & 1;
  // staging coords
  const int ar = tid >> 1, ah = tid & 1;       // A: row, 16-float half
  const int br = tid >> 2, bc = tid & 3;       // B: row, 8-bf16 chunk

  f32x4 acc[4][2] = {};
  for (int k0 = 0; k0 < K; k0 += 32) {
    __syncthreads();
    { // stage A (f32 -> hi/lo bf16)
      const float* src = X + (size_t)(m0 + ar) * K + k0 + ah * 16;
      #pragma unroll
      for (int g = 0; g < 2; ++g) {
        float4 u = *(const float4*)(src + g * 8);
        float4 w = *(const float4*)(src + g * 8 + 4);
        float f[8] = {u.x, u.y, u.z, u.w, w.x, w.y, w.z, w.w};
        bf16x8 hv, lv;
        #pragma unroll
        for (int j = 0; j < 8; ++j) {
          ush hb = f2bf(f[j]);
          hv[j] = (short)hb;
          lv[j] = (short)f2bf(f[j] - bf2f(hb));
        }
        *(bf16x8*)&Ash[ar][ah * 16 + g * 8] = hv;
        *(bf16x8*)&Asl[ar][ah * 16 + g * 8] = lv;
      }
    }
    { // stage B (pre-split planes)
      bf16x8 bh = {}, bl = {};
      if (n0 + br < N) {
        bh = *(const bf16x8*)(Wh + (size_t)(n0 + br) * K + k0 + bc * 8);
        bl = *(const bf16x8*)(Wl + (size_t)(n0 + br) * K + k0 + bc * 8);
      }
      *(bf16x8*)&Bsh[br][bc * 8] = bh;
      *(bf16x8*)&Bsl[br][bc * 8] = bl;
    }
    __syncthreads();
    bf16x8 Ah[4], Al[4], Bh[2], Bl[2];
    #pragma unroll
    for (int mt = 0; mt < 4; ++mt) {
      Ah[mt] = *(const bf16x8*)&Ash[wm * 64 + mt * 16 + cc][quad * 8];
      Al[mt] = *(const bf16x8*)&Asl[wm * 64 + mt * 16 + cc][quad * 8];
    }
    #pragma unroll
    for (int nt = 0; nt < 2; ++nt) {
      Bh[nt] = *(const bf16x8*)&Bsh[wn * 32 + nt * 16 + cc][quad * 8];
      Bl[nt] = *(const bf16x8*)&Bsl[wn * 32 + nt * 16 + cc][quad * 8];
    }
    #pragma unroll
    for (int mt = 0; mt < 4; ++mt)
      #pragma unroll
      for (int nt = 0; nt < 2; ++nt) {
        acc[mt][nt] = __builtin_amdgcn_mfma_f32_16x16x32_bf16(Ah[mt], Bh[nt], acc[mt][nt], 0, 0, 0);
        acc[mt][nt] = __builtin_amdgcn_mfma_f32_16x16x32_bf16(Ah[mt], Bl[nt], acc[mt][nt], 0, 0, 0);
        acc[mt][nt] = __builtin_amdgcn_mfma_f32_16x16x32_bf16(Al[mt], Bh[nt], acc[mt][nt], 0, 0, 0);
      }
  }
  #pragma unroll
  for (int mt = 0; mt < 4; ++mt)
    #pragma unroll
    for (int nt = 0; nt < 2; ++nt) {
      int m = m0 + wm * 64 + mt * 16 + quad * 4;
      int n = n0 + wn * 32 + nt * 16 + cc;
      if (n < N) {
        #pragma unroll
        for (int r = 0; r < 4; ++r)
          Y[(size_t)(m + r) * N + n] = acc[mt][nt][r];
      }
    }
}

// ---------------- cast f32 -> bf16 (q, k, v in one contiguous range) ----------
__global__ __launch_bounds__(256) void cast_bf16(const float* __restrict__ src,
    ush* __restrict__ dst, int n4)
{
  int i = blockIdx.x * 256 + threadIdx.x;
  if (i < n4) {
    float4 v = ((const float4*)src)[i];
    ushort4 o;
    o.x = f2bf(v.x); o.y = f2bf(v.y); o.z = f2bf(v.z); o.w = f2bf(v.w);
    ((ushort4*)dst)[i] = o;
  }
}

// ---------------- mean-pool k,v into 32 block centroids -----------------------
__global__ void pool_kv(const float* __restrict__ k, const float* __restrict__ v,
                        float* __restrict__ kc, float* __restrict__ vc)
{
  int c = blockIdx.x, d = threadIdx.x;
  float sk = 0.f, sv = 0.f;
  for (int i = 0; i < BS; ++i) {
    sk += k[(size_t)(c*BS + i)*HD + d];
    sv += v[(size_t)(c*BS + i)*HD + d];
  }
  kc[c*HD + d] = sk * (1.f/BS);
  vc[c*HD + d] = sv * (1.f/BS);
}

// ------ compressed attention + top-k block selection (one WG per token) -------
// f32 end-to-end (selection-critical). Softmax: 16 lanes/head shuffle
// butterflies. Top-k: one-wave argmax butterfly, jax tie-break (smaller idx).
__global__ __launch_bounds__(256) void cmp_attn(const float* __restrict__ q,
    const float* __restrict__ kc, const float* __restrict__ vc,
    float* __restrict__ ocmp, int* __restrict__ blkp)
{
  const int t = blockIdx.x, tid = threadIdx.x;
  __shared__ float qs[1024];
  __shared__ float scs[16][33];
  __shared__ float ps[16][33];
  ((float4*)qs)[tid] = ((const float4*)q)[(size_t)t*256 + tid];
  __syncthreads();
  // scores: 16 heads x 32 blocks = 512 dots of 64; 2 per thread
  #pragma unroll
  for (int p = 0; p < 2; ++p) {
    int pair = tid + 256*p;
    int h = pair >> 5, c = pair & 31;
    const float4* kc4 = (const float4*)(kc + c*HD);
    const float4* q4  = (const float4*)(qs + h*HD);
    float a = 0.f;
    #pragma unroll
    for (int d4 = 0; d4 < 16; ++d4) {
      float4 kv = kc4[d4], qv = q4[d4];
      a += qv.x*kv.x + qv.y*kv.y + qv.z*kv.z + qv.w*kv.w;
    }
    scs[h][c] = a * 0.125f;
  }
  __syncthreads();
  const int nvis = (t + 1) >> 6;
  { // softmax: thread (h = tid>>4, i = tid&15) handles blocks i and i+16
    const int h = tid >> 4, i = tid & 15;
    float s0 = (i      < nvis) ? scs[h][i]      : -INFINITY;
    float s1 = (i + 16 < nvis) ? scs[h][i + 16] : -INFINITY;
    float m = fmaxf(s0, s1);
    #pragma unroll
    for (int off = 1; off < 16; off <<= 1) m = fmaxf(m, __shfl_xor(m, off));
    float e0 = (i      < nvis) ? expf(s0 - m) : 0.f;
    float e1 = (i + 16 < nvis) ? expf(s1 - m) : 0.f;
    float l = e0 + e1;
    #pragma unroll
    for (int off = 1; off < 16; off <<= 1) l += __shfl_xor(l, off);
    float inv = (l > 0.f) ? 1.f / l : 0.f;
    ps[h][i]      = e0 * inv;
    ps[h][i + 16] = e1 * inv;
  }
  __syncthreads();
  { // o_cmp = p @ v_c : thread (h = tid>>4, d4 = tid&15) -> float4 output
    const int h = tid >> 4, d4 = tid & 15;
    const float4* vc4 = (const float4*)vc;
    float4 a = make_float4(0.f, 0.f, 0.f, 0.f);
    #pragma unroll 8
    for (int c = 0; c < 32; ++c) {
      float p = ps[h][c];
      float4 vv = vc4[c*16 + d4];
      a.x += p*vv.x; a.y += p*vv.y; a.z += p*vv.z; a.w += p*vv.w;
    }
    ((float4*)(ocmp + (size_t)t*DM))[tid] = a;
  }
  // top-k on wave 0: lane c holds importance of block c; argmax butterfly
  if (tid < 64) {
    const int cur = t >> 6;
    float a = -INFINITY;
    if (tid < 32) {
      float s = 0.f;
      #pragma unroll
      for (int h = 0; h < 16; ++h) s += ps[h][tid];
      a = (tid <= cur) ? s : NEGF;
      if (tid == 0 || tid == cur) a = INFINITY;
    }
    for (int s = 0; s < S_SEL; ++s) {
      float bv = a; int bi = tid;
      #pragma unroll
      for (int off = 1; off < 64; off <<= 1) {
        float ov = __shfl_xor(bv, off); int oi = __shfl_xor(bi, off);
        if (ov > bv || (ov == bv && oi < bi)) { bv = ov; bi = oi; }
      }
      if (tid == 0) blkp[t*S_SEL + s] = bi;
      if (tid == bi) a = -INFINITY;
    }
  }
}

// ------ selected block-sparse attention via MFMA; one WG (4 waves) per token --
#define KSW 72
#define VTW 136
#define PBW 1032
__global__ __launch_bounds__(256) void sel_attn_mfma(
    const ush* __restrict__ qb, const ush* __restrict__ kb,
    const ush* __restrict__ vb, const float* __restrict__ gp,
    const int* __restrict__ blkp, float* __restrict__ ocmp_io)
{
  const int t = blockIdx.x, tid = threadIdx.x;
  const int w = tid >> 6, lane = tid & 63;
  const int quad = lane >> 4, c = lane & 15;

  __shared__ ush Pb[16][PBW];
  __shared__ ush KV[64 * VTW];
  __shared__ int   blk_s[16];
  __shared__ float redm[4][16], redl[4][16];
  __shared__ float gm[16], invl[16], gc[16], gs[16];

  if (tid < 16) {
    blk_s[tid] = blkp[t*S_SEL + tid];
    float a = gp[(size_t)t*48 + tid*3 + 0];
    float b = gp[(size_t)t*48 + tid*3 + 1];
    gc[tid] = 1.f/(1.f + __expf(-a));
    gs[tid] = 1.f/(1.f + __expf(-b));
  }

  const ush* qrow = qb + (size_t)t*DM + c*HD + quad*8;
  bf16x8 qa0 = *(const bf16x8*)(qrow);
  bf16x8 qa1 = *(const bf16x8*)(qrow + 32);

  f32x4 S[16];
  for (int b = 0; b < 16; ++b) {
    __syncthreads();
    {
      const int base = blk_s[b] * (BS*HD);
      #pragma unroll
      for (int rep = 0; rep < 2; ++rep) {
        int i = tid*2 + rep;
        int tok = i >> 3, colb = (i & 7) * 8;
        bf16x8 kvv = *(const bf16x8*)(kb + base + i*8);
        *(bf16x8*)&KV[tok*KSW + colb] = kvv;
      }
    }
    __syncthreads();
    const int srow = w*16 + c;
    bf16x8 b0 = *(const bf16x8*)&KV[srow*KSW + quad*8];
    bf16x8 b1 = *(const bf16x8*)&KV[srow*KSW + 32 + quad*8];
    f32x4 acc = {0.f, 0.f, 0.f, 0.f};
    acc = __builtin_amdgcn_mfma_f32_16x16x32_bf16(qa0, b0, acc, 0, 0, 0);
    acc = __builtin_amdgcn_mfma_f32_16x16x32_bf16(qa1, b1, acc, 0, 0, 0);
    const int tok = blk_s[b]*BS + w*16 + c;
    const bool ok = (tok <= t);
    #pragma unroll
    for (int r = 0; r < 4; ++r) S[b][r] = ok ? acc[r]*0.125f : NEGF;
  }

  f32x4 mx = S[0];
  #pragma unroll
  for (int b = 1; b < 16; ++b) {
    #pragma unroll
    for (int r = 0; r < 4; ++r) mx[r] = fmaxf(mx[r], S[b][r]);
  }
  #pragma unroll
  for (int off = 1; off < 16; off <<= 1) {
    #pragma unroll
    for (int r = 0; r < 4; ++r) mx[r] = fmaxf(mx[r], __shfl_xor(mx[r], off));
  }
  if (c == 0) {
    #pragma unroll
    for (int r = 0; r < 4; ++r) redm[w][quad*4 + r] = mx[r];
  }
  __syncthreads();
  if (tid < 16)
    gm[tid] = fmaxf(fmaxf(redm[0][tid], redm[1][tid]),
                    fmaxf(redm[2][tid], redm[3][tid]));
  __syncthreads();
  f32x4 M;
  #pragma unroll
  for (int r = 0; r < 4; ++r) M[r] = gm[quad*4 + r];

  f32x4 lsum = {0.f, 0.f, 0.f, 0.f};
  #pragma unroll
  for (int b = 0; b < 16; ++b) {
    #pragma unroll
    for (int r = 0; r < 4; ++r) {
      ush pbv = f2bf(__expf(S[b][r] - M[r]));
      Pb[quad*4 + r][b*64 + w*16 + c] = pbv;
      lsum[r] += bf2f(pbv);
    }
  }
  #pragma unroll
  for (int off = 1; off < 16; off <<= 1) {
    #pragma unroll
    for (int r = 0; r < 4; ++r) lsum[r] += __shfl_xor(lsum[r], off);
  }
  if (c == 0) {
    #pragma unroll
    for (int r = 0; r < 4; ++r) redl[w][quad*4 + r] = lsum[r];
  }
  __syncthreads();
  if (tid < 16)
    invl[tid] = 1.f / (redl[0][tid] + redl[1][tid] + redl[2][tid] + redl[3][tid]);
  __syncthreads();

  f32x4 accO = {0.f, 0.f, 0.f, 0.f};
  const int p = tid & 63, dg = tid >> 6, d0 = dg*16;
  for (int ci = 0; ci < 8; ++ci) {
    __syncthreads();
    {
      const int tloc = 2*p;
      const int blk  = blk_s[2*ci + (tloc >> 6)];
      const int gtok = blk*BS + (tloc & 63);
      const ush* v0 = vb + (size_t)gtok*HD + d0;
      bf16x8 a0 = *(const bf16x8*)(v0);
      bf16x8 a1 = *(const bf16x8*)(v0 + 8);
      bf16x8 c0 = *(const bf16x8*)(v0 + 64);
      bf16x8 c1 = *(const bf16x8*)(v0 + 72);
      #pragma unroll
      for (int i = 0; i < 8; ++i) {
        *(unsigned int*)&KV[(d0+i)*VTW + tloc]   = (ush)a0[i] | ((unsigned int)(ush)c0[i] << 16);
        *(unsigned int*)&KV[(d0+8+i)*VTW + tloc] = (ush)a1[i] | ((unsigned int)(ush)c1[i] << 16);
      }
    }
    __syncthreads();
    #pragma unroll
    for (int kk = 0; kk < 4; ++kk) {
      bf16x8 A = *(const bf16x8*)&Pb[c][128*ci + 32*kk + quad*8];
      bf16x8 B = *(const bf16x8*)&KV[(16*w + c)*VTW + 32*kk + quad*8];
      accO = __builtin_amdgcn_mfma_f32_16x16x32_bf16(A, B, accO, 0, 0, 0);
    }
  }

  const int d = 16*w + c;
  #pragma unroll
  for (int r = 0; r < 4; ++r) {
    const int h = quad*4 + r;
    size_t idx = (size_t)t*DM + h*HD + d;
    float val = accO[r] * invl[h] * gs[h] + ocmp_io[idx] * gc[h];
    ocmp_io[idx] = val;
  }
}

extern "C" void kernel_launch(void* const* d_in, const int* in_sizes, int n_in,
                              void* d_out, int out_size, void* d_ws, size_t ws_size,
                              hipStream_t stream)
{
  const float* x  = (const float*)d_in[0];
  const float* Wq = (const float*)d_in[1];
  const float* Wk = (const float*)d_in[2];
  const float* Wv = (const float*)d_in[3];
  const float* Wg = (const float*)d_in[4];
  const float* Wo = (const float*)d_in[5];
  float* out = (float*)d_out;

  float* ws  = (float*)d_ws;
  float* q    = ws;                           // 2048*1024
  float* kbuf = q    + (size_t)T_TOK*DM;      // 2048*64
  float* vbuf = kbuf + (size_t)T_TOK*HD;      // 2048*64
  float* gpj  = vbuf + (size_t)T_TOK*HD;      // 2048*48
  float* kc   = gpj  + (size_t)T_TOK*48;      // 32*64
  float* vc   = kc   + NB*HD;                 // 32*64
  float* ocmp = vc   + NB*HD;                 // 2048*1024
  int*   blkp = (int*)(ocmp + (size_t)T_TOK*DM);                 // 2048*16
  ush*   qkvb = (ush*)(blkp + T_TOK*S_SEL);   // 2048*1152 bf16
  ush* qb = qkvb;
  ush* kb = qb + (size_t)T_TOK*DM;
  ush* vb = kb + (size_t)T_TOK*HD;
  ush* Wqh = qkvb + (size_t)T_TOK*(DM + 2*HD);
  ush* Wql = Wqh + 1048576;
  ush* Wkh = Wql + 1048576;
  ush* Wkl = Wkh + 65536;
  ush* Wvh = Wkl + 65536;
  ush* Wvl = Wvh + 65536;
  ush* Wgh = Wvl + 65536;
  ush* Wgl = Wgh + 49152;
  ush* Woh = Wgl + 49152;
  ush* Wol = Woh + 1048576;

  split_w<<<dim3(1024, 5), 256, 0, stream>>>(Wq, Wk, Wv, Wg, Wo,
      Wqh, Wql, Wkh, Wkl, Wvh, Wvl, Wgh, Wgl, Woh, Wol);
  gemm_split<<<dim3(16, 16), 256, 0, stream>>>(x, Wqh, Wql, q,    DM, DM);
  gemm_split<<<dim3(1,  16), 256, 0, stream>>>(x, Wkh, Wkl, kbuf, HD, DM);
  gemm_split<<<dim3(1,  16), 256, 0, stream>>>(x, Wvh, Wvl, vbuf, HD, DM);
  gemm_split<<<dim3(1,  16), 256, 0, stream>>>(x, Wgh, Wgl, gpj,  48, DM);
  pool_kv<<<NB, HD, 0, stream>>>(kbuf, vbuf, kc, vc);
  {
    int n4 = T_TOK * (DM + 2*HD) / 4;
    cast_bf16<<<(n4 + 255)/256, 256, 0, stream>>>(q, qkvb, n4);
  }
  cmp_attn<<<T_TOK, 256, 0, stream>>>(q, kc, vc, ocmp, blkp);
  sel_attn_mfma<<<T_TOK, 256, 0, stream>>>(qb, kb, vb, gpj, blkp, ocmp);
  gemm_split<<<dim3(16, 16), 256, 0, stream>>>(ocmp, Woh, Wol, out, DM, DM);
}

// Round 4
// 247.795 us; speedup vs baseline: 3.5132x; 1.6356x over previous
//
#include <hip/hip_runtime.h>
#include <math.h>

#define T_TOK 2048
#define DM 1024
#define HQ 16
#define HD 64
#define NB 32
#define BS 64
#define S_SEL 16
#define NEGF (-1e30f)

typedef __attribute__((ext_vector_type(8))) short bf16x8;
typedef __attribute__((ext_vector_type(4))) float f32x4;
typedef unsigned short ush;

__device__ __forceinline__ ush f2bf(float x) {
  unsigned u = __float_as_uint(x);
  return (ush)((u + 0x7fffu + ((u >> 16) & 1u)) >> 16);
}
__device__ __forceinline__ float bf2f(ush h) {
  return __uint_as_float(((unsigned)h) << 16);
}

// ---- decompose the 5 weight arrays into bf16 hi/lo planes (one launch) ------
__global__ __launch_bounds__(256) void split_w(
    const float* __restrict__ s0, const float* __restrict__ s1,
    const float* __restrict__ s2, const float* __restrict__ s3,
    const float* __restrict__ s4,
    ush* h0, ush* l0, ush* h1, ush* l1, ush* h2, ush* l2,
    ush* h3, ush* l3, ush* h4, ush* l4)
{
  const float* srcs[5] = {s0, s1, s2, s3, s4};
  ush* hs[5] = {h0, h1, h2, h3, h4};
  ush* ls[5] = {l0, l1, l2, l3, l4};
  const int ns[5] = {1048576, 65536, 65536, 49152, 1048576};
  int seg = blockIdx.y;
  int i = (blockIdx.x * 256 + threadIdx.x) * 4;
  if (i >= ns[seg]) return;
  float4 v = *(const float4*)(srcs[seg] + i);
  ushort4 hv, lv;
  hv.x = f2bf(v.x); lv.x = f2bf(v.x - bf2f(hv.x));
  hv.y = f2bf(v.y); lv.y = f2bf(v.y - bf2f(hv.y));
  hv.z = f2bf(v.z); lv.z = f2bf(v.z - bf2f(hv.z));
  hv.w = f2bf(v.w); lv.w = f2bf(v.w - bf2f(hv.w));
  *(ushort4*)(hs[seg] + i) = hv;
  *(ushort4*)(ls[seg] + i) = lv;
}

// ---- split-bf16 MFMA GEMM body: Y = X @ W^T, 64x64 tile, BK=32 --------------
// 4 waves 2x2; wave tile 32x32; 12 MFMAs/iter. Optional f32 / bf16-hi/lo out.
__device__ __forceinline__ void gemm64_body(const float* __restrict__ X,
    const ush* __restrict__ Wh, const ush* __restrict__ Wl,
    float* Yf, ush* Yh, ush* Yl, int N, int K, int m0, int n0,
    ush Ash[64][40], ush Asl[64][40], ush Bsh[64][40], ush Bsl[64][40])
{
  const int tid = threadIdx.x;
  const int wave = tid >> 6, lane = tid & 63;
  const int quad = lane >> 4, c16 = lane & 15;
  const int wm = wave >> 1, wn = wave & 1;
  const int ar = tid >> 2, ac = (tid & 3) * 8;
  f32x4 acc[2][2] = {};
  for (int k0 = 0; k0 < K; k0 += 32) {
    __syncthreads();
    { // stage A (f32 -> hi/lo) and B (pre-split planes)
      const float* src = X + (size_t)(m0 + ar) * K + k0 + ac;
      float4 u = *(const float4*)(src);
      float4 w2 = *(const float4*)(src + 4);
      float f[8] = {u.x, u.y, u.z, u.w, w2.x, w2.y, w2.z, w2.w};
      bf16x8 hv, lv;
      #pragma unroll
      for (int j = 0; j < 8; ++j) {
        ush hb = f2bf(f[j]);
        hv[j] = (short)hb;
        lv[j] = (short)f2bf(f[j] - bf2f(hb));
      }
      *(bf16x8*)&Ash[ar][ac] = hv;
      *(bf16x8*)&Asl[ar][ac] = lv;
      bf16x8 bh = {}, bl = {};
      if (n0 + ar < N) {
        bh = *(const bf16x8*)(Wh + (size_t)(n0 + ar) * K + k0 + ac);
        bl = *(const bf16x8*)(Wl + (size_t)(n0 + ar) * K + k0 + ac);
      }
      *(bf16x8*)&Bsh[ar][ac] = bh;
      *(bf16x8*)&Bsl[ar][ac] = bl;
    }
    __syncthreads();
    bf16x8 Ah[2], Al[2], Bh[2], Bl[2];
    #pragma unroll
    for (int mt = 0; mt < 2; ++mt) {
      Ah[mt] = *(const bf16x8*)&Ash[wm*32 + mt*16 + c16][quad*8];
      Al[mt] = *(const bf16x8*)&Asl[wm*32 + mt*16 + c16][quad*8];
    }
    #pragma unroll
    for (int nt = 0; nt < 2; ++nt) {
      Bh[nt] = *(const bf16x8*)&Bsh[wn*32 + nt*16 + c16][quad*8];
      Bl[nt] = *(const bf16x8*)&Bsl[wn*32 + nt*16 + c16][quad*8];
    }
    #pragma unroll
    for (int mt = 0; mt < 2; ++mt)
      #pragma unroll
      for (int nt = 0; nt < 2; ++nt) {
        acc[mt][nt] = __builtin_amdgcn_mfma_f32_16x16x32_bf16(Ah[mt], Bh[nt], acc[mt][nt], 0, 0, 0);
        acc[mt][nt] = __builtin_amdgcn_mfma_f32_16x16x32_bf16(Ah[mt], Bl[nt], acc[mt][nt], 0, 0, 0);
        acc[mt][nt] = __builtin_amdgcn_mfma_f32_16x16x32_bf16(Al[mt], Bh[nt], acc[mt][nt], 0, 0, 0);
      }
  }
  #pragma unroll
  for (int mt = 0; mt < 2; ++mt)
    #pragma unroll
    for (int nt = 0; nt < 2; ++nt) {
      int n = n0 + wn*32 + nt*16 + c16;
      if (n < N) {
        #pragma unroll
        for (int r = 0; r < 4; ++r) {
          int m = m0 + wm*32 + mt*16 + quad*4 + r;
          float vvv = acc[mt][nt][r];
          if (Yf) Yf[(size_t)m*N + n] = vvv;
          if (Yh) {
            ush hb = f2bf(vvv);
            Yh[(size_t)m*N + n] = hb;
            if (Yl) Yl[(size_t)m*N + n] = f2bf(vvv - bf2f(hb));
          }
        }
      }
    }
}

__global__ __launch_bounds__(256) void gemm_split(const float* __restrict__ X,
    const ush* __restrict__ Wh, const ush* __restrict__ Wl,
    float* Yf, ush* Yh, ush* Yl, int N, int K)
{
  __shared__ ush Ash[64][40], Asl[64][40], Bsh[64][40], Bsl[64][40];
  gemm64_body(X, Wh, Wl, Yf, Yh, Yl, N, K, blockIdx.y*64, blockIdx.x*64,
              Ash, Asl, Bsh, Bsl);
}

// fused k/v/g projections: blockIdx.x = segment
__global__ __launch_bounds__(256) void gemm_kvg(const float* __restrict__ X,
    const ush* __restrict__ Wkh, const ush* __restrict__ Wkl,
    const ush* __restrict__ Wvh, const ush* __restrict__ Wvl,
    const ush* __restrict__ Wgh, const ush* __restrict__ Wgl,
    float* kbuf, ush* kb, float* vbuf, ush* vb, float* gpj, int K)
{
  __shared__ ush Ash[64][40], Asl[64][40], Bsh[64][40], Bsl[64][40];
  const int seg = blockIdx.x;
  const ush *wh, *wl; float* yf; ush* yh = nullptr; int N;
  if (seg == 0)      { wh = Wkh; wl = Wkl; yf = kbuf; yh = kb; N = 64; }
  else if (seg == 1) { wh = Wvh; wl = Wvl; yf = vbuf; yh = vb; N = 64; }
  else               { wh = Wgh; wl = Wgl; yf = gpj;  N = 48; }
  gemm64_body(X, wh, wl, yf, yh, nullptr, N, K, blockIdx.y*64, 0,
              Ash, Asl, Bsh, Bsl);
}

// ---- mean-pool k,v into centroids, emit split-bf16 (kc [c][d], vcT [d][c]) --
__global__ void pool_kv(const float* __restrict__ k, const float* __restrict__ v,
    ush* __restrict__ kch, ush* __restrict__ kcl,
    ush* __restrict__ vth, ush* __restrict__ vtl)
{
  int c = blockIdx.x, d = threadIdx.x;
  float sk = 0.f, sv = 0.f;
  for (int i = 0; i < BS; ++i) {
    sk += k[(size_t)(c*BS + i)*HD + d];
    sv += v[(size_t)(c*BS + i)*HD + d];
  }
  sk *= (1.f/BS); sv *= (1.f/BS);
  ush kh = f2bf(sk);
  kch[c*HD + d] = kh;
  kcl[c*HD + d] = f2bf(sk - bf2f(kh));
  ush vh = f2bf(sv);
  vth[d*NB + c] = vh;
  vtl[d*NB + c] = f2bf(sv - bf2f(vh));
}

// ---- compressed attention + top-k, MFMA, ONE WAVE PER TOKEN (4 tokens/WG) ---
// scores: split-bf16 Q·Kc^T (6 MFMAs); softmax+importance in registers;
// topk: 64-lane argmax butterfly; o_cmp: split-bf16 P·Vc (12 MFMAs).
__global__ __launch_bounds__(256) void cmp_attn_mfma(
    const ush* __restrict__ qh, const ush* __restrict__ ql,
    const ush* __restrict__ kch, const ush* __restrict__ kcl,
    const ush* __restrict__ vth, const ush* __restrict__ vtl,
    float* __restrict__ ocmp, int* __restrict__ blkp)
{
  __shared__ float Pls[4][16][36];
  const int tid = threadIdx.x, w = tid >> 6, lane = tid & 63;
  const int quad = lane >> 4, c16 = lane & 15;
  const int t = blockIdx.x * 4 + w;

  // Q A-frags (m = head = c16), hi/lo, 2 k-chunks (d 0-31, 32-63)
  const ush* qrh = qh + (size_t)t*DM + c16*HD + quad*8;
  const ush* qrl = ql + (size_t)t*DM + c16*HD + quad*8;
  bf16x8 qah0 = *(const bf16x8*)(qrh);
  bf16x8 qah1 = *(const bf16x8*)(qrh + 32);
  bf16x8 qal0 = *(const bf16x8*)(qrl);
  bf16x8 qal1 = *(const bf16x8*)(qrl + 32);

  // scores S[h][c], two n-halves of 16 blocks
  f32x4 s[2];
  #pragma unroll
  for (int nh = 0; nh < 2; ++nh) {
    const int crow = nh*16 + c16;
    bf16x8 kh0 = *(const bf16x8*)(kch + crow*HD + quad*8);
    bf16x8 kh1 = *(const bf16x8*)(kch + crow*HD + 32 + quad*8);
    bf16x8 kl0 = *(const bf16x8*)(kcl + crow*HD + quad*8);
    bf16x8 kl1 = *(const bf16x8*)(kcl + crow*HD + 32 + quad*8);
    f32x4 acc = {0.f, 0.f, 0.f, 0.f};
    acc = __builtin_amdgcn_mfma_f32_16x16x32_bf16(qah0, kh0, acc, 0, 0, 0);
    acc = __builtin_amdgcn_mfma_f32_16x16x32_bf16(qah1, kh1, acc, 0, 0, 0);
    acc = __builtin_amdgcn_mfma_f32_16x16x32_bf16(qah0, kl0, acc, 0, 0, 0);
    acc = __builtin_amdgcn_mfma_f32_16x16x32_bf16(qah1, kl1, acc, 0, 0, 0);
    acc = __builtin_amdgcn_mfma_f32_16x16x32_bf16(qal0, kh0, acc, 0, 0, 0);
    acc = __builtin_amdgcn_mfma_f32_16x16x32_bf16(qal1, kh1, acc, 0, 0, 0);
    s[nh] = acc;
  }

  // softmax over visible blocks (c < nvis); p in registers (C layout)
  const int nvis = (t + 1) >> 6;
  const bool visA = (c16 < nvis), visB = (16 + c16 < nvis);
  float p[2][4];
  float iA = 0.f, iB = 0.f;
  #pragma unroll
  for (int r = 0; r < 4; ++r) {
    float sA = s[0][r] * 0.125f, sB = s[1][r] * 0.125f;
    float m = fmaxf(visA ? sA : -INFINITY, visB ? sB : -INFINITY);
    #pragma unroll
    for (int off = 1; off < 16; off <<= 1) m = fmaxf(m, __shfl_xor(m, off));
    float eA = visA ? __expf(sA - m) : 0.f;
    float eB = visB ? __expf(sB - m) : 0.f;
    float l = eA + eB;
    #pragma unroll
    for (int off = 1; off < 16; off <<= 1) l += __shfl_xor(l, off);
    float inv = (l > 0.f) ? 1.f / l : 0.f;
    p[0][r] = eA * inv; p[1][r] = eB * inv;
    iA += p[0][r]; iB += p[1][r];
  }
  // importance: sum over heads = over (quad, r); cross-quad via xor 16/32
  iA += __shfl_xor(iA, 16); iA += __shfl_xor(iA, 32);
  iB += __shfl_xor(iB, 16); iB += __shfl_xor(iB, 32);

  // stash P (C layout h=quad*4+r, c) for the A-layout reload
  #pragma unroll
  for (int nh = 0; nh < 2; ++nh)
    #pragma unroll
    for (int r = 0; r < 4; ++r)
      Pls[w][quad*4 + r][nh*16 + c16] = p[nh][r];

  // top-k (lane c holds imp[c] for c<32; jax tie-break: smaller index)
  {
    const int cur = t >> 6;
    float a;
    if (lane < 16) a = iA;
    else if (lane < 32) a = iB;
    else a = -INFINITY;
    if (lane < 32) {
      if (lane > cur) a = NEGF;
      if (lane == 0 || lane == cur) a = INFINITY;
    }
    for (int sidx = 0; sidx < S_SEL; ++sidx) {
      float bv = a; int bi = lane;
      #pragma unroll
      for (int off = 1; off < 64; off <<= 1) {
        float ov = __shfl_xor(bv, off); int oi = __shfl_xor(bi, off);
        if (ov > bv || (ov == bv && oi < bi)) { bv = ov; bi = oi; }
      }
      if (lane == 0) blkp[t*S_SEL + sidx] = bi;
      if (lane == bi) a = -INFINITY;
    }
  }
  __syncthreads();

  // reload P in A layout (m=h=c16, k=c=quad*8+j), split hi/lo
  float4 pa = *(const float4*)&Pls[w][c16][quad*8];
  float4 pb = *(const float4*)&Pls[w][c16][quad*8 + 4];
  float pf[8] = {pa.x, pa.y, pa.z, pa.w, pb.x, pb.y, pb.z, pb.w};
  bf16x8 pah, pal;
  #pragma unroll
  for (int j = 0; j < 8; ++j) {
    ush hb = f2bf(pf[j]);
    pah[j] = (short)hb;
    pal[j] = (short)f2bf(pf[j] - bf2f(hb));
  }
  // o_cmp = P @ Vc : K=32 (one chunk), 4 n-chunks of 16 dims
  #pragma unroll
  for (int nb = 0; nb < 4; ++nb) {
    const int drow = nb*16 + c16;
    bf16x8 vh8 = *(const bf16x8*)(vth + drow*NB + quad*8);
    bf16x8 vl8 = *(const bf16x8*)(vtl + drow*NB + quad*8);
    f32x4 acc = {0.f, 0.f, 0.f, 0.f};
    acc = __builtin_amdgcn_mfma_f32_16x16x32_bf16(pah, vh8, acc, 0, 0, 0);
    acc = __builtin_amdgcn_mfma_f32_16x16x32_bf16(pah, vl8, acc, 0, 0, 0);
    acc = __builtin_amdgcn_mfma_f32_16x16x32_bf16(pal, vh8, acc, 0, 0, 0);
    #pragma unroll
    for (int r = 0; r < 4; ++r)
      ocmp[(size_t)t*DM + (quad*4 + r)*HD + nb*16 + c16] = acc[r];
  }
}

// ------ selected block-sparse attention via MFMA; one WG (4 waves) per token --
#define KSW 72
#define VTW 136
#define PBW 1032
__global__ __launch_bounds__(256) void sel_attn_mfma(
    const ush* __restrict__ qb, const ush* __restrict__ kb,
    const ush* __restrict__ vb, const float* __restrict__ gp,
    const int* __restrict__ blkp, float* __restrict__ ocmp_io)
{
  const int t = blockIdx.x, tid = threadIdx.x;
  const int w = tid >> 6, lane = tid & 63;
  const int quad = lane >> 4, c = lane & 15;

  __shared__ ush Pb[16][PBW];
  __shared__ ush KV[64 * VTW];
  __shared__ int   blk_s[16];
  __shared__ float redm[4][16], redl[4][16];
  __shared__ float gm[16], invl[16], gc[16], gs[16];

  if (tid < 16) {
    blk_s[tid] = blkp[t*S_SEL + tid];
    float a = gp[(size_t)t*48 + tid*3 + 0];
    float b = gp[(size_t)t*48 + tid*3 + 1];
    gc[tid] = 1.f/(1.f + __expf(-a));
    gs[tid] = 1.f/(1.f + __expf(-b));
  }

  const ush* qrow = qb + (size_t)t*DM + c*HD + quad*8;
  bf16x8 qa0 = *(const bf16x8*)(qrow);
  bf16x8 qa1 = *(const bf16x8*)(qrow + 32);

  f32x4 S[16];
  for (int b = 0; b < 16; ++b) {
    __syncthreads();
    {
      const int base = blk_s[b] * (BS*HD);
      #pragma unroll
      for (int rep = 0; rep < 2; ++rep) {
        int i = tid*2 + rep;
        int tok = i >> 3, colb = (i & 7) * 8;
        bf16x8 kvv = *(const bf16x8*)(kb + base + i*8);
        *(bf16x8*)&KV[tok*KSW + colb] = kvv;
      }
    }
    __syncthreads();
    const int srow = w*16 + c;
    bf16x8 b0 = *(const bf16x8*)&KV[srow*KSW + quad*8];
    bf16x8 b1 = *(const bf16x8*)&KV[srow*KSW + 32 + quad*8];
    f32x4 acc = {0.f, 0.f, 0.f, 0.f};
    acc = __builtin_amdgcn_mfma_f32_16x16x32_bf16(qa0, b0, acc, 0, 0, 0);
    acc = __builtin_amdgcn_mfma_f32_16x16x32_bf16(qa1, b1, acc, 0, 0, 0);
    const int tok = blk_s[b]*BS + w*16 + c;
    const bool ok = (tok <= t);
    #pragma unroll
    for (int r = 0; r < 4; ++r) S[b][r] = ok ? acc[r]*0.125f : NEGF;
  }

  f32x4 mx = S[0];
  #pragma unroll
  for (int b = 1; b < 16; ++b) {
    #pragma unroll
    for (int r = 0; r < 4; ++r) mx[r] = fmaxf(mx[r], S[b][r]);
  }
  #pragma unroll
  for (int off = 1; off < 16; off <<= 1) {
    #pragma unroll
    for (int r = 0; r < 4; ++r) mx[r] = fmaxf(mx[r], __shfl_xor(mx[r], off));
  }
  if (c == 0) {
    #pragma unroll
    for (int r = 0; r < 4; ++r) redm[w][quad*4 + r] = mx[r];
  }
  __syncthreads();
  if (tid < 16)
    gm[tid] = fmaxf(fmaxf(redm[0][tid], redm[1][tid]),
                    fmaxf(redm[2][tid], redm[3][tid]));
  __syncthreads();
  f32x4 M;
  #pragma unroll
  for (int r = 0; r < 4; ++r) M[r] = gm[quad*4 + r];

  f32x4 lsum = {0.f, 0.f, 0.f, 0.f};
  #pragma unroll
  for (int b = 0; b < 16; ++b) {
    #pragma unroll
    for (int r = 0; r < 4; ++r) {
      ush pbv = f2bf(__expf(S[b][r] - M[r]));
      Pb[quad*4 + r][b*64 + w*16 + c] = pbv;
      lsum[r] += bf2f(pbv);
    }
  }
  #pragma unroll
  for (int off = 1; off < 16; off <<= 1) {
    #pragma unroll
    for (int r = 0; r < 4; ++r) lsum[r] += __shfl_xor(lsum[r], off);
  }
  if (c == 0) {
    #pragma unroll
    for (int r = 0; r < 4; ++r) redl[w][quad*4 + r] = lsum[r];
  }
  __syncthreads();
  if (tid < 16)
    invl[tid] = 1.f / (redl[0][tid] + redl[1][tid] + redl[2][tid] + redl[3][tid]);
  __syncthreads();

  f32x4 accO = {0.f, 0.f, 0.f, 0.f};
  const int p = tid & 63, dg = tid >> 6, d0 = dg*16;
  for (int ci = 0; ci < 8; ++ci) {
    __syncthreads();
    {
      const int tloc = 2*p;
      const int blk  = blk_s[2*ci + (tloc >> 6)];
      const int gtok = blk*BS + (tloc & 63);
      const ush* v0 = vb + (size_t)gtok*HD + d0;
      bf16x8 a0 = *(const bf16x8*)(v0);
      bf16x8 a1 = *(const bf16x8*)(v0 + 8);
      bf16x8 c0 = *(const bf16x8*)(v0 + 64);
      bf16x8 c1 = *(const bf16x8*)(v0 + 72);
      #pragma unroll
      for (int i = 0; i < 8; ++i) {
        *(unsigned int*)&KV[(d0+i)*VTW + tloc]   = (ush)a0[i] | ((unsigned int)(ush)c0[i] << 16);
        *(unsigned int*)&KV[(d0+8+i)*VTW + tloc] = (ush)a1[i] | ((unsigned int)(ush)c1[i] << 16);
      }
    }
    __syncthreads();
    #pragma unroll
    for (int kk = 0; kk < 4; ++kk) {
      bf16x8 A = *(const bf16x8*)&Pb[c][128*ci + 32*kk + quad*8];
      bf16x8 B = *(const bf16x8*)&KV[(16*w + c)*VTW + 32*kk + quad*8];
      accO = __builtin_amdgcn_mfma_f32_16x16x32_bf16(A, B, accO, 0, 0, 0);
    }
  }

  const int d = 16*w + c;
  #pragma unroll
  for (int r = 0; r < 4; ++r) {
    const int h = quad*4 + r;
    size_t idx = (size_t)t*DM + h*HD + d;
    float val = accO[r] * invl[h] * gs[h] + ocmp_io[idx] * gc[h];
    ocmp_io[idx] = val;
  }
}

extern "C" void kernel_launch(void* const* d_in, const int* in_sizes, int n_in,
                              void* d_out, int out_size, void* d_ws, size_t ws_size,
                              hipStream_t stream)
{
  const float* x  = (const float*)d_in[0];
  const float* Wq = (const float*)d_in[1];
  const float* Wk = (const float*)d_in[2];
  const float* Wv = (const float*)d_in[3];
  const float* Wg = (const float*)d_in[4];
  const float* Wo = (const float*)d_in[5];
  float* out = (float*)d_out;

  float* ws   = (float*)d_ws;
  float* kbuf = ws;                                // 2048*64 f32
  float* vbuf = kbuf + (size_t)T_TOK*HD;
  float* gpj  = vbuf + (size_t)T_TOK*HD;           // 2048*48 f32
  float* ocmp = gpj  + (size_t)T_TOK*48;           // 2048*1024 f32
  int*   blkp = (int*)(ocmp + (size_t)T_TOK*DM);   // 2048*16
  ush* qbh = (ush*)(blkp + T_TOK*S_SEL);           // 2048*1024 bf16 (hi)
  ush* qbl = qbh + (size_t)T_TOK*DM;               // lo plane
  ush* kb  = qbl + (size_t)T_TOK*DM;               // 2048*64
  ush* vb  = kb  + (size_t)T_TOK*HD;
  ush* kch = vb  + (size_t)T_TOK*HD;               // 32*64
  ush* kcl = kch + NB*HD;
  ush* vth = kcl + NB*HD;                          // 64*32 (transposed)
  ush* vtl = vth + NB*HD;
  ush* Wqh = vtl + NB*HD;
  ush* Wql = Wqh + 1048576;
  ush* Wkh = Wql + 1048576;
  ush* Wkl = Wkh + 65536;
  ush* Wvh = Wkl + 65536;
  ush* Wvl = Wvh + 65536;
  ush* Wgh = Wvl + 65536;
  ush* Wgl = Wgh + 49152;
  ush* Woh = Wgl + 49152;
  ush* Wol = Woh + 1048576;

  split_w<<<dim3(1024, 5), 256, 0, stream>>>(Wq, Wk, Wv, Wg, Wo,
      Wqh, Wql, Wkh, Wkl, Wvh, Wvl, Wgh, Wgl, Woh, Wol);
  // q projection: bf16 hi/lo only (no f32 consumer)
  gemm_split<<<dim3(16, 32), 256, 0, stream>>>(x, Wqh, Wql, nullptr, qbh, qbl, DM, DM);
  // fused k/v/g projections
  gemm_kvg<<<dim3(3, 32), 256, 0, stream>>>(x, Wkh, Wkl, Wvh, Wvl, Wgh, Wgl,
      kbuf, kb, vbuf, vb, gpj, DM);
  pool_kv<<<NB, HD, 0, stream>>>(kbuf, vbuf, kch, kcl, vth, vtl);
  cmp_attn_mfma<<<T_TOK/4, 256, 0, stream>>>(qbh, qbl, kch, kcl, vth, vtl, ocmp, blkp);
  sel_attn_mfma<<<T_TOK, 256, 0, stream>>>(qbh, kb, vb, gpj, blkp, ocmp);
  gemm_split<<<dim3(16, 32), 256, 0, stream>>>(ocmp, Woh, Wol, out, nullptr, nullptr, DM, DM);
}